// Round 2
// baseline (1186.461 us; speedup 1.0000x reference)
//
#include <hip/hip_runtime.h>

#define BB 8
#define XX 256
#define CC 256
#define TC 8          // c-rows per k_all block
#define TCE 4         // c-rows per epilogue call (epilogue unchanged from R7)
#define G  8          // x-group size for the register double-buffer pipeline
#define NCH 4         // x-chunks; matches R7's SPLIT=4 fold tree bitwise
#define XCH (XX / NCH)

// R9 = R8 resubmitted verbatim: R8's bench died with "MI355X container
// failed twice" (infra acquire failure -- no pass/fail, no counters, no
// absmax). Kernel audit found no hang/fault candidate: uniform barriers,
// in-bounds accesses, aligned float2/float4 loads, no ws use, no
// graph-capture-hostile API calls. Re-running the same experiment.
//
// R8 rationale: rocprof top-5 was ALL __amd_rocclr_fillBufferAligned writing
// 256 MiB (~41 us each) -- the harness re-poisoning d_ws every timed
// iteration. Our three kernels summed to ~10 us of real work, so the
// measured 83.7 us was dominated by ws-poison + 3x dispatch overhead.
// R8/R9 never touch d_ws:
//   k_zero (256 KB out clear)  +  k_all (u recompute + gram dist + epilogue)
// Arithmetic is bitwise-identical to R7: same per-chunk x order (4 chunks of
// 64, sequential G=8 groups), same fmaf(-2,gacc,Sc+Sd) per chunk, same
// ((w0+w1)+w2)+w3 fold, same dAd^2 multiply, unchanged epilogue.

// ---------------- shared epilogue (bitwise R5/R6/R7) ----------------

__device__ __forceinline__ void epilogue(
    float dist0, float dist1, float dist2, float dist3,
    int b, int c0, int d, const float* __restrict__ gu,
    float* __restrict__ out, float (*wmax)[4])
{
    float ed[TCE];
    ed[0] = (d == c0)     ? 0.0f : __fdiv_rn(1.0f, __fadd_rn(dist0, 1e-10f));
    ed[1] = (d == c0 + 1) ? 0.0f : __fdiv_rn(1.0f, __fadd_rn(dist1, 1e-10f));
    ed[2] = (d == c0 + 2) ? 0.0f : __fdiv_rn(1.0f, __fadd_rn(dist2, 1e-10f));
    ed[3] = (d == c0 + 3) ? 0.0f : __fdiv_rn(1.0f, __fadd_rn(dist3, 1e-10f));

    const int wave = threadIdx.x >> 6;
    const int lane = threadIdx.x & 63;
#pragma unroll
    for (int j = 0; j < TCE; ++j) {
        float v = ed[j];
#pragma unroll
        for (int m = 1; m < 64; m <<= 1) v = fmaxf(v, __shfl_xor(v, m));
        if (lane == 0) wmax[j][wave] = v;
    }
    __syncthreads();

#pragma unroll
    for (int j = 0; j < TCE; ++j) {
        const int c = c0 + j;
        float em = fmaxf(fmaxf(wmax[j][0], wmax[j][1]), fmaxf(wmax[j][2], wmax[j][3]));
        float p;
        if (d == c) {
            p = 0.99f;
        } else {
            p = __fmul_rn(__fdiv_rn(ed[j], em), 0.99f);
        }
        float logit = logf(__fdiv_rn(p, __fsub_rn(1.0f, p)));

        const float2 g2 = *(const float2*)(gu + (((size_t)b * CC + c) * CC + d) * 2);
        float g0 = -logf(-logf(g2.x));
        float g1 = -logf(-logf(g2.y));

        float a0 = __fadd_rn(logit, g0);
        float a1 = __fadd_rn(-logit, g1);
        float m  = fmaxf(a0, a1);
        float e0 = expf(__fsub_rn(a0, m));
        float e1 = expf(__fsub_rn(a1, m));
        float s  = __fadd_rn(e0, e1);
        float y0 = __fdiv_rn(e0, s);
        float y1 = __fdiv_rn(e1, s);
        if (y0 > y1) {
            atomicAdd(&out[(size_t)c * CC + d], 0.125f);
        }
    }
}

// ---------------- out zeroing (replaces memset dispatch) ----------------

__global__ __launch_bounds__(256) void k_zero(float* __restrict__ out)
{
    // 64 blocks * 256 threads * 16 B = 256 KB, exact cover of out
    ((float4*)out)[blockIdx.x * 256 + threadIdx.x] = make_float4(0.f, 0.f, 0.f, 0.f);
}

// ---------------- fused kernel ----------------

#define ULOAD2(BA, BP, GIDX) {                                   \
    const float* _a = aChunk + (size_t)(GIDX) * G * CC;          \
    const float* _p = pChunk + (size_t)(GIDX) * G * CC;          \
    _Pragma("unroll")                                            \
    for (int i = 0; i < G; ++i) {                                \
        BA[i] = _a[(size_t)i * CC];                              \
        BP[i] = _p[(size_t)i * CC];                              \
    } }

#define UCOMP2(BA, BP, GIDX) {                                   \
    const int _xb = xc0 + (GIDX) * G;                            \
    _Pragma("unroll")                                            \
    for (int i = 0; i < G; ++i) {                                \
        const float udv = __fadd_rn(__fmul_rn(wa, BA[i]),        \
                                    __fmul_rn(wp, BP[i]));       \
        const float4 cA = colsU[_xb + i][0];                     \
        const float4 cB = colsU[_xb + i][1];                     \
        gacc0 = fmaf(cA.x, udv, gacc0);                          \
        gacc1 = fmaf(cA.y, udv, gacc1);                          \
        gacc2 = fmaf(cA.z, udv, gacc2);                          \
        gacc3 = fmaf(cA.w, udv, gacc3);                          \
        gacc4 = fmaf(cB.x, udv, gacc4);                          \
        gacc5 = fmaf(cB.y, udv, gacc5);                          \
        gacc6 = fmaf(cB.z, udv, gacc6);                          \
        gacc7 = fmaf(cB.w, udv, gacc7);                          \
        sacc  = fmaf(udv, udv, sacc);                            \
    } }

__global__ __launch_bounds__(256, 2) void k_all(
    const float* __restrict__ amp, const float* __restrict__ ph,
    const float* __restrict__ A,   const float* __restrict__ wAp,
    const float* __restrict__ wPp, const float* __restrict__ gu,
    float* __restrict__ out)
{
    const int d  = threadIdx.x;
    const int c0 = blockIdx.x * TC;
    const int b  = blockIdx.y;

    const float wa = wAp[0];
    const float wp = wPp[0];

    __shared__ float4 colsU[XX][2];   // u[b, x, c0..c0+7], 8 KB
    __shared__ float  sS[CC];         // per-chunk S_d exchange
    __shared__ float  wmax[TCE][4];

    // Stage u columns c0..c0+7 for all x (same formula as R7's k_u -> same bits)
    {
        const int x = threadIdx.x;
        const size_t base = ((size_t)b * XX + x) * CC + c0;
        const float4 a0 = *(const float4*)(amp + base);
        const float4 p0 = *(const float4*)(ph  + base);
        const float4 a1 = *(const float4*)(amp + base + 4);
        const float4 p1 = *(const float4*)(ph  + base + 4);
        float4 u0, u1;
        u0.x = __fadd_rn(__fmul_rn(wa, a0.x), __fmul_rn(wp, p0.x));
        u0.y = __fadd_rn(__fmul_rn(wa, a0.y), __fmul_rn(wp, p0.y));
        u0.z = __fadd_rn(__fmul_rn(wa, a0.z), __fmul_rn(wp, p0.z));
        u0.w = __fadd_rn(__fmul_rn(wa, a0.w), __fmul_rn(wp, p0.w));
        u1.x = __fadd_rn(__fmul_rn(wa, a1.x), __fmul_rn(wp, p1.x));
        u1.y = __fadd_rn(__fmul_rn(wa, a1.y), __fmul_rn(wp, p1.y));
        u1.z = __fadd_rn(__fmul_rn(wa, a1.z), __fmul_rn(wp, p1.z));
        u1.w = __fadd_rn(__fmul_rn(wa, a1.w), __fmul_rn(wp, p1.w));
        colsU[x][0] = u0;
        colsU[x][1] = u1;
    }
    __syncthreads();

    const float* aCol = amp + (size_t)b * XX * CC + d;
    const float* pCol = ph  + (size_t)b * XX * CC + d;

    float w0 = 0.f, w1 = 0.f, w2 = 0.f, w3 = 0.f;
    float w4 = 0.f, w5 = 0.f, w6 = 0.f, w7 = 0.f;

#pragma unroll
    for (int h = 0; h < NCH; ++h) {
        const int xc0 = h * XCH;
        const float* aChunk = aCol + (size_t)xc0 * CC;
        const float* pChunk = pCol + (size_t)xc0 * CC;

        float gacc0 = 0.f, gacc1 = 0.f, gacc2 = 0.f, gacc3 = 0.f;
        float gacc4 = 0.f, gacc5 = 0.f, gacc6 = 0.f, gacc7 = 0.f, sacc = 0.f;

        constexpr int NGH = XCH / G;   // 8
        float b0A[G], b0P[G], b1A[G], b1P[G];
        ULOAD2(b0A, b0P, 0)
        for (int g = 0; g + 2 < NGH; g += 2) {
            ULOAD2(b1A, b1P, g + 1)
            UCOMP2(b0A, b0P, g)
            ULOAD2(b0A, b0P, g + 2)
            UCOMP2(b1A, b1P, g + 1)
        }
        ULOAD2(b1A, b1P, NGH - 1)
        UCOMP2(b0A, b0P, NGH - 2)
        UCOMP2(b1A, b1P, NGH - 1)

        __syncthreads();          // previous chunk's sS readers are done
        sS[d] = sacc;
        __syncthreads();

        // per-chunk partial, identical chain to R7's k_dist store
        const float t0 = fmaf(-2.0f, gacc0, __fadd_rn(sS[c0 + 0], sacc));
        const float t1 = fmaf(-2.0f, gacc1, __fadd_rn(sS[c0 + 1], sacc));
        const float t2 = fmaf(-2.0f, gacc2, __fadd_rn(sS[c0 + 2], sacc));
        const float t3 = fmaf(-2.0f, gacc3, __fadd_rn(sS[c0 + 3], sacc));
        const float t4 = fmaf(-2.0f, gacc4, __fadd_rn(sS[c0 + 4], sacc));
        const float t5 = fmaf(-2.0f, gacc5, __fadd_rn(sS[c0 + 5], sacc));
        const float t6 = fmaf(-2.0f, gacc6, __fadd_rn(sS[c0 + 6], sacc));
        const float t7 = fmaf(-2.0f, gacc7, __fadd_rn(sS[c0 + 7], sacc));
        if (h == 0) {
            w0 = t0; w1 = t1; w2 = t2; w3 = t3;
            w4 = t4; w5 = t5; w6 = t6; w7 = t7;
        } else {
            // same left-associated fold as R7's k_epi: ((w0+w1)+w2)+w3
            w0 = __fadd_rn(w0, t0); w1 = __fadd_rn(w1, t1);
            w2 = __fadd_rn(w2, t2); w3 = __fadd_rn(w3, t3);
            w4 = __fadd_rn(w4, t4); w5 = __fadd_rn(w5, t5);
            w6 = __fadd_rn(w6, t6); w7 = __fadd_rn(w7, t7);
        }
    }

    const float dAd  = A[(size_t)d * CC + d];
    const float dAd2 = __fmul_rn(dAd, dAd);

    epilogue(__fmul_rn(dAd2, w0), __fmul_rn(dAd2, w1),
             __fmul_rn(dAd2, w2), __fmul_rn(dAd2, w3),
             b, c0, d, gu, out, wmax);
    __syncthreads();   // wmax reuse barrier between the two epilogue calls
    epilogue(__fmul_rn(dAd2, w4), __fmul_rn(dAd2, w5),
             __fmul_rn(dAd2, w6), __fmul_rn(dAd2, w7),
             b, c0 + 4, d, gu, out, wmax);
}

extern "C" void kernel_launch(void* const* d_in, const int* in_sizes, int n_in,
                              void* d_out, int out_size, void* d_ws, size_t ws_size,
                              hipStream_t stream) {
    const float* amp = (const float*)d_in[0];
    const float* ph  = (const float*)d_in[1];
    const float* A   = (const float*)d_in[2];
    const float* wa  = (const float*)d_in[3];
    const float* wp  = (const float*)d_in[4];
    const float* gu  = (const float*)d_in[5];
    float* out = (float*)d_out;

    (void)d_ws; (void)ws_size;   // R9: workspace intentionally unused

    k_zero<<<(CC * CC / 4) / 256, 256, 0, stream>>>(out);
    dim3 g(CC / TC, BB);
    k_all<<<g, 256, 0, stream>>>(amp, ph, A, wa, wp, gu, out);
}